// Round 2
// baseline (6019.794 us; speedup 1.0000x reference)
//
#include <hip/hip_runtime.h>
#include <math.h>

// N=100000 nodes, E=1600000 edges, HID=64, C=2, fp32.
// Workspace budget is tight (R1 post-timing divergence was consistent with
// out-of-workspace writes corrupting the harness's pristine input copies at
// ~85MB usage) -> total ws use here is ~33.6MB:
//   h (25.6MB) + csr (6.4MB) + rn/dinv/counts/offsets/cursor (~1.6MB)
// agg/h1 are never materialized in HBM: the edge pass and the whole epilogue
// are fused into one kernel (k_main) with 32-node LDS tiles.

__device__ __forceinline__ void fma4(float (&acc)[4], float a, const float4& w) {
    acc[0] = fmaf(a, w.x, acc[0]);
    acc[1] = fmaf(a, w.y, acc[1]);
    acc[2] = fmaf(a, w.z, acc[2]);
    acc[3] = fmaf(a, w.w, acc[3]);
}

// stage 32 rows x 64 cols from global into LDS (stride 68: 2-way bank alias only,
// 272B row pitch keeps float4 alignment)
__device__ __forceinline__ void load_rows(const float* __restrict__ src, int row0, int n,
                                          float (*dst)[68], int t)
{
    int e = t * 8;
    int r = e >> 6, i = e & 63;
    int grow = row0 + r;
    float4 v0 = make_float4(0.f, 0.f, 0.f, 0.f), v1 = v0;
    if (grow < n) {
        const float* p = src + (size_t)grow * 64 + i;
        v0 = *(const float4*)p;
        v1 = *(const float4*)(p + 4);
    }
    *(float4*)&dst[r][i]     = v0;
    *(float4*)&dst[r][i + 4] = v1;
}

// 32x64 tile GEMM core: thread (rg,cg) computes rows {2rg,2rg+1} x cols [4cg,4cg+4)
// w/b may be LDS or global pointers (global weight reads are L1-resident, 16KB)
__device__ __forceinline__ void gemm_core(const float (*in)[68], const float* __restrict__ w,
                                          const float* __restrict__ b, int rg, int cg,
                                          float (&acc0)[4], float (&acc1)[4])
{
#pragma unroll
    for (int dc = 0; dc < 4; dc++) { float bb = b[4*cg + dc]; acc0[dc] = bb; acc1[dc] = bb; }
    const int r0 = 2 * rg, r1 = 2 * rg + 1;
#pragma unroll
    for (int i = 0; i < 64; i += 4) {
        float4 a0 = *(const float4*)&in[r0][i];
        float4 a1 = *(const float4*)&in[r1][i];
        float4 q0 = *(const float4*)&w[(i + 0) * 64 + 4 * cg];
        float4 q1 = *(const float4*)&w[(i + 1) * 64 + 4 * cg];
        float4 q2 = *(const float4*)&w[(i + 2) * 64 + 4 * cg];
        float4 q3 = *(const float4*)&w[(i + 3) * 64 + 4 * cg];
        fma4(acc0, a0.x, q0); fma4(acc0, a0.y, q1); fma4(acc0, a0.z, q2); fma4(acc0, a0.w, q3);
        fma4(acc1, a1.x, q0); fma4(acc1, a1.y, q1); fma4(acc1, a1.z, q2); fma4(acc1, a1.w, q3);
    }
}

// MODE: 0 = none, 1 = relu, 2 = tanh
template <int MODE>
__device__ __forceinline__ void gemm_lds(const float (*in)[68], const float* __restrict__ w,
                                         const float* __restrict__ b, float (*out)[68],
                                         int rg, int cg)
{
    float a0[4], a1[4];
    gemm_core(in, w, b, rg, cg, a0, a1);
#pragma unroll
    for (int dc = 0; dc < 4; dc++) {
        float v0 = a0[dc], v1 = a1[dc];
        if (MODE == 1) { v0 = fmaxf(v0, 0.f); v1 = fmaxf(v1, 0.f); }
        if (MODE == 2) { v0 = tanhf(v0); v1 = tanhf(v1); }
        a0[dc] = v0; a1[dc] = v1;
    }
    *(float4*)&out[2 * rg][4 * cg]     = make_float4(a0[0], a0[1], a0[2], a0[3]);
    *(float4*)&out[2 * rg + 1][4 * cg] = make_float4(a1[0], a1[1], a1[2], a1[3]);
}

__device__ __forceinline__ void gemm_global(const float (*in)[68], const float* __restrict__ w,
                                            const float* __restrict__ b, float* __restrict__ out,
                                            int row0, int n, int rg, int cg)
{
    float a0[4], a1[4];
    gemm_core(in, w, b, rg, cg, a0, a1);
    int r0 = row0 + 2 * rg, r1 = r0 + 1;
    if (r0 < n) *(float4*)&out[(size_t)r0 * 64 + 4 * cg] = make_float4(a0[0], a0[1], a0[2], a0[3]);
    if (r1 < n) *(float4*)&out[(size_t)r1 * 64 + 4 * cg] = make_float4(a1[0], a1[1], a1[2], a1[3]);
}

// ---------------- CSR build ----------------

__global__ __launch_bounds__(256) void k_zero(int* __restrict__ counts, int* __restrict__ cursor, int n)
{
    int i = blockIdx.x * 256 + threadIdx.x;
    if (i < n) { counts[i] = 0; cursor[i] = 0; }
}

__global__ __launch_bounds__(256) void k_count(const int* __restrict__ col, int* __restrict__ counts, int e)
{
    int i = blockIdx.x * 256 + threadIdx.x;
    if (i < e) atomicAdd(&counts[col[i]], 1);
}

__global__ __launch_bounds__(1024) void k_scan(const int* __restrict__ counts, int* __restrict__ offsets, int n)
{
    __shared__ int s[1024];
    int t = threadIdx.x;
    int chunk = (n + 1023) / 1024;
    int start = t * chunk;
    int end = min(n, start + chunk);
    int tot = 0;
    for (int i = start; i < end; i++) tot += counts[i];
    s[t] = tot;
    __syncthreads();
    for (int d = 1; d < 1024; d <<= 1) {
        int v = (t >= d) ? s[t - d] : 0;
        __syncthreads();
        s[t] += v;
        __syncthreads();
    }
    int run = s[t] - tot;  // exclusive prefix for this chunk
    for (int i = start; i < end; i++) { offsets[i] = run; run += counts[i]; }
    if (t == 1023) offsets[n] = s[1023];
}

__global__ __launch_bounds__(256) void k_fill(const int* __restrict__ row, const int* __restrict__ col,
                                              const int* __restrict__ offsets, int* __restrict__ cursor,
                                              int* __restrict__ csr, int e)
{
    int i = blockIdx.x * 256 + threadIdx.x;
    if (i < e) {
        int c = col[i];
        int p = atomicAdd(&cursor[c], 1);
        csr[offsets[c] + p] = row[i];
    }
}

// ---------------- node MLP ----------------

__global__ __launch_bounds__(256) void k_mlp(const float* __restrict__ x,
    const float* __restrict__ w1, const float* __restrict__ b1,
    const float* __restrict__ w2, const float* __restrict__ b2,
    const float* __restrict__ w3, const float* __restrict__ b3,
    float* __restrict__ h, int n)
{
    __shared__ float w1s[4096], w2s[4096], w3s[4096];
    __shared__ float b1s[64], b2s[64], b3s[64];
    __shared__ float xs[32][68], hs[32][68];
    int t = threadIdx.x;
    for (int i = t; i < 4096; i += 256) { w1s[i] = w1[i]; w2s[i] = w2[i]; w3s[i] = w3[i]; }
    if (t < 64) { b1s[t] = b1[t]; b2s[t] = b2[t]; b3s[t] = b3[t]; }
    __syncthreads();
    int cg = t & 15, rg = t >> 4;
    for (int row0 = blockIdx.x * 32; row0 < n; row0 += gridDim.x * 32) {
        load_rows(x, row0, n, xs, t);
        __syncthreads();
        gemm_lds<1>(xs, w1s, b1s, hs, rg, cg);
        __syncthreads();
        gemm_lds<1>(hs, w2s, b2s, xs, rg, cg);
        __syncthreads();
        gemm_global(xs, w3s, b3s, h, row0, n, rg, cg);
        __syncthreads();
    }
}

// ---------------- per-node scalars ----------------

__global__ __launch_bounds__(256) void k_rn(const float* __restrict__ h,
    const int* __restrict__ offsets, float* __restrict__ rn,
    float* __restrict__ dinv, int n)
{
    int node = blockIdx.x * 4 + (threadIdx.x >> 6);
    if (node >= n) return;
    int lane = threadIdx.x & 63;
    float v = h[(size_t)node * 64 + lane];
    float s = v * v;
#pragma unroll
    for (int d = 1; d < 64; d <<= 1) s += __shfl_xor(s, d, 64);
    if (lane == 0) {
        rn[node] = 1.0f / (sqrtf(s) + 1e-12f);
        float deg = (float)(offsets[node + 1] - offsets[node] + 1);  // +1 self loop
        dinv[node] = rsqrtf(deg);
    }
}

// ---------------- fused edge pass + epilogue ----------------
// Per 32-node tile:
//  gather phase (wave per node, 8 nodes/wave):
//    A[r][:] = agg = dinv_c * (dinv_c*h_c + sum dinv_r*h_r)
//    D[r][:] = h_c
//    yp[r]   = (h1 . wc[64:128,:])  folded AGNN classifier contribution
//  epilogue phase (block-wide tile GEMMs, weights from global/L1):
//    B = tanh(D@wx+bx) = xp ; C = A@wg1+bg1 = f0 ; D = A@wg2+bg2 = f1
//    logits fused (no p0/p1 tiles): l_k[row] = sum_j tanh((f_k@wf+bf)[row][j])*xp[row][j]
//    softmax -> res = s0*f0+s1*f1 -> y = res@wc[0:64,:] + yp + bc
__global__ __launch_bounds__(256) void k_main(const float* __restrict__ h,
    const int* __restrict__ offsets, const int* __restrict__ csr,
    const float* __restrict__ rn, const float* __restrict__ dinv,
    const float* __restrict__ beta_p,
    const float* __restrict__ wg1, const float* __restrict__ bg1,
    const float* __restrict__ wg2, const float* __restrict__ bg2,
    const float* __restrict__ wf,  const float* __restrict__ bf,
    const float* __restrict__ wx,  const float* __restrict__ bx,
    const float* __restrict__ wc,  const float* __restrict__ bc,
    float* __restrict__ y, int n, int ntiles)
{
    __shared__ float A[32][68], B[32][68], C[32][68], D[32][68];
    __shared__ float yp[32][2], ll[32][2];
    int t = threadIdx.x;
    int wave = t >> 6, lane = t & 63;
    int cg = t & 15, rg = t >> 4;
    int tr = t >> 3, tp = t & 7;
    float beta = beta_p[0];
    float2 wch = ((const float2*)wc)[64 + lane];   // wc[(64+lane)*2 + {0,1}]

    for (int tile = blockIdx.x; tile < ntiles; tile += gridDim.x) {
        int row0 = tile * 32;
        // ---- gather phase: this wave handles tile rows wave*8 .. wave*8+7
        for (int rr = 0; rr < 8; rr++) {
            int r = wave * 8 + rr;
            int node = row0 + r;
            if (node < n) {
                size_t nb = (size_t)node * 64;
                float hc = h[nb + lane];
                float ss = hc * hc;
#pragma unroll
                for (int d = 1; d < 64; d <<= 1) ss += __shfl_xor(ss, d, 64);
                float rnc = rn[node];
                float dc  = dinv[node];
                float wself = expf(beta * ss * rnc * rnc);
                float accA = dc * hc;
                float accN = wself * hc;
                float denom = wself;
                int off = offsets[node];
                int cnt = offsets[node + 1] - off;
                for (int k0 = 0; k0 < cnt; k0 += 64) {
                    int m = min(64, cnt - k0);
                    int idx = 0; float rv = 0.f, dv = 0.f;
                    if (lane < m) {
                        idx = csr[off + k0 + lane];
                        rv  = rn[idx];
                        dv  = dinv[idx];
                    }
                    int   r_cur  = __shfl(idx, 0, 64);
                    float hr_cur = h[(size_t)r_cur * 64 + lane];
                    for (int k = 0; k < m; k++) {
                        float hr = hr_cur;
                        if (k + 1 < m) {   // prefetch next source row under the reduce
                            int nidx = __shfl(idx, k + 1, 64);
                            hr_cur = h[(size_t)nidx * 64 + lane];
                        }
                        float rnr = __shfl(rv, k, 64);
                        float dvr = __shfl(dv, k, 64);
                        float p = hc * hr;
#pragma unroll
                        for (int d = 1; d < 64; d <<= 1) p += __shfl_xor(p, d, 64);
                        float w = expf(beta * p * rnc * rnr);
                        accA  = fmaf(dvr, hr, accA);
                        accN  = fmaf(w,  hr, accN);
                        denom += w;
                    }
                }
                A[r][lane] = dc * accA;
                D[r][lane] = hc;
                float h1v = accN / denom;
                float cx = h1v * wch.x, cy = h1v * wch.y;
#pragma unroll
                for (int d = 1; d < 64; d <<= 1) { cx += __shfl_xor(cx, d, 64); cy += __shfl_xor(cy, d, 64); }
                if (lane == 0) { yp[r][0] = cx; yp[r][1] = cy; }
            } else {
                A[r][lane] = 0.f; D[r][lane] = 0.f;
                if (lane == 0) { yp[r][0] = 0.f; yp[r][1] = 0.f; }
            }
        }
        __syncthreads();
        // P1: B = xp = tanh(h@wx+bx)   (reads D=h)
        gemm_lds<2>(D, wx, bx, B, rg, cg);
        __syncthreads();
        // P2: C = f0, D = f1   (both read A; D's old content dead)
        gemm_lds<0>(A, wg1, bg1, C, rg, cg);
        gemm_lds<0>(A, wg2, bg2, D, rg, cg);
        __syncthreads();
        // P3: fused logit GEMMs (p0/p1 never materialized)
        {
            float a0[4], a1[4];
            float t0, t1;
            gemm_core(C, wf, bf, rg, cg, a0, a1);
            t0 = 0.f; t1 = 0.f;
#pragma unroll
            for (int dc = 0; dc < 4; dc++) {
                t0 = fmaf(tanhf(a0[dc]), B[2 * rg][4 * cg + dc], t0);
                t1 = fmaf(tanhf(a1[dc]), B[2 * rg + 1][4 * cg + dc], t1);
            }
#pragma unroll
            for (int d = 1; d < 16; d <<= 1) { t0 += __shfl_xor(t0, d, 64); t1 += __shfl_xor(t1, d, 64); }
            if (cg == 0) { ll[2 * rg][0] = t0; ll[2 * rg + 1][0] = t1; }
            gemm_core(D, wf, bf, rg, cg, a0, a1);
            t0 = 0.f; t1 = 0.f;
#pragma unroll
            for (int dc = 0; dc < 4; dc++) {
                t0 = fmaf(tanhf(a0[dc]), B[2 * rg][4 * cg + dc], t0);
                t1 = fmaf(tanhf(a1[dc]), B[2 * rg + 1][4 * cg + dc], t1);
            }
#pragma unroll
            for (int d = 1; d < 16; d <<= 1) { t0 += __shfl_xor(t0, d, 64); t1 += __shfl_xor(t1, d, 64); }
            if (cg == 0) { ll[2 * rg][1] = t0; ll[2 * rg + 1][1] = t1; }
        }
        __syncthreads();
        // P4: softmax fusion + classifier (8 threads per row)
        {
            int row = row0 + tr;
            float l0 = ll[tr][0], l1 = ll[tr][1];
            float mx = fmaxf(l0, l1);
            float e0 = expf(l0 - mx), e1 = expf(l1 - mx);
            float inv = 1.0f / (e0 + e1);
            float s0 = e0 * inv, s1 = e1 * inv;
            float y0 = 0.f, y1 = 0.f;
#pragma unroll
            for (int u = 0; u < 8; u++) {
                int j = tp * 8 + u;
                float res = s0 * C[tr][j] + s1 * D[tr][j];
                float2 wcj = ((const float2*)wc)[j];
                y0 = fmaf(res, wcj.x, y0);
                y1 = fmaf(res, wcj.y, y1);
            }
#pragma unroll
            for (int d = 1; d < 8; d <<= 1) { y0 += __shfl_xor(y0, d, 64); y1 += __shfl_xor(y1, d, 64); }
            if (tp == 0 && row < n) {
                y[(size_t)row * 2 + 0] = y0 + yp[tr][0] + bc[0];
                y[(size_t)row * 2 + 1] = y1 + yp[tr][1] + bc[1];
            }
        }
        __syncthreads();
    }
}

extern "C" void kernel_launch(void* const* d_in, const int* in_sizes, int n_in,
                              void* d_out, int out_size, void* d_ws, size_t ws_size,
                              hipStream_t stream)
{
    const float* x    = (const float*)d_in[0];
    const int*   ei   = (const int*)d_in[1];
    const float* w1   = (const float*)d_in[2];
    const float* b1   = (const float*)d_in[3];
    const float* w2   = (const float*)d_in[4];
    const float* b2   = (const float*)d_in[5];
    const float* w3   = (const float*)d_in[6];
    const float* b3   = (const float*)d_in[7];
    const float* wg1  = (const float*)d_in[8];
    const float* bg1  = (const float*)d_in[9];
    const float* wg2  = (const float*)d_in[10];
    const float* bg2  = (const float*)d_in[11];
    const float* beta = (const float*)d_in[12];
    const float* wf   = (const float*)d_in[13];
    const float* bf   = (const float*)d_in[14];
    const float* wx   = (const float*)d_in[15];
    const float* bx   = (const float*)d_in[16];
    const float* wc   = (const float*)d_in[17];
    const float* bc   = (const float*)d_in[18];
    float* y = (float*)d_out;

    int n = in_sizes[0] / 64;     // 100000
    int e = in_sizes[1] / 2;      // 1600000
    const int* row = ei;
    const int* col = ei + e;

    // workspace layout: ~33.6MB total
    char* p = (char*)d_ws;
    auto alloc = [&](size_t bytes) { char* q = p; p += (bytes + 255) & ~(size_t)255; return q; };
    float* h     = (float*)alloc((size_t)n * 64 * 4);   // 25.6MB
    int* csr     = (int*)alloc((size_t)e * 4);          // 6.4MB
    float* rn    = (float*)alloc((size_t)n * 4);
    float* dinv  = (float*)alloc((size_t)n * 4);
    int* counts  = (int*)alloc((size_t)n * 4);
    int* offsets = (int*)alloc((size_t)(n + 1) * 4);
    int* cursor  = (int*)alloc((size_t)n * 4);

    int ntiles = (n + 31) / 32;

    k_zero<<<(n + 255) / 256, 256, 0, stream>>>(counts, cursor, n);
    k_count<<<(e + 255) / 256, 256, 0, stream>>>(col, counts, e);
    k_scan<<<1, 1024, 0, stream>>>(counts, offsets, n);
    k_fill<<<(e + 255) / 256, 256, 0, stream>>>(row, col, offsets, cursor, csr, e);
    k_mlp<<<800, 256, 0, stream>>>(x, w1, b1, w2, b2, w3, b3, h, n);
    k_rn<<<(n + 3) / 4, 256, 0, stream>>>(h, offsets, rn, dinv, n);
    k_main<<<1024, 256, 0, stream>>>(h, offsets, csr, rn, dinv, beta,
                                     wg1, bg1, wg2, bg2, wf, bf, wx, bx, wc, bc,
                                     y, n, ntiles);
}